// Round 4
// baseline (2888.861 us; speedup 1.0000x reference)
//
#include <hip/hip_runtime.h>

#define H 128
#define TDEPTH 10
#define NPT 1023      // nodes per tree
#define NTREES 512

typedef unsigned short bf16_t;

__device__ __forceinline__ float sig_(float x) { return 1.0f / (1.0f + __expf(-x)); }
// tanh via exp, safe at +/- overflow
__device__ __forceinline__ float th_(float x)  { return 1.0f - 2.0f / (__expf(2.0f * x) + 1.0f); }

__device__ __forceinline__ float b2f(bf16_t u) {
    union { float f; unsigned int u; } v; v.u = ((unsigned int)u) << 16; return v.f;
}
__device__ __forceinline__ bf16_t f2b(float f) {
    union { float f; unsigned int u; } v; v.f = f;
    unsigned int r = (v.u + 0x7fffu + ((v.u >> 16) & 1u)) >> 16;   // RNE
    return (bf16_t)r;
}

// ---------------------------------------------------------------------------
// Leaf kernel: 32 nodes/block, 256 threads. iou = x@W_iou.T + b_iou + b_Uiou
// ---------------------------------------------------------------------------
__global__ __launch_bounds__(256, 2) void leaf_kernel(
    const int* __restrict__ wordid, const float* __restrict__ E,
    const float* __restrict__ W_iou, const float* __restrict__ b_iou,
    const float* __restrict__ b_Uiou,
    bf16_t* __restrict__ h_cur, bf16_t* __restrict__ c_cur, int t0)
{
    const int level = TDEPTH - 1;  // 9
    __shared__ __align__(16) float x_s[32][H];
    __shared__ __align__(16) float w_s[3][H][8];

    const int tid = threadIdx.x;
    const int g0  = blockIdx.x * 32;

    // stage x = E[wordid[id]] for 32 nodes
    for (int idx = tid; idx < 32 * (H / 4); idx += 256) {
        int m = idx >> 5;
        int q = idx & 31;
        int g = g0 + m;
        int t = g >> level;
        int i = g - (t << level);
        int id = (t0 + t) * NPT + ((1 << level) - 1) + i;
        int wid = wordid[id];
        ((float4*)x_s[m])[q] = ((const float4*)(E + (long)wid * H))[q];
    }

    const int j  = tid & 127;
    const int mg = tid >> 7;
    float ai[16], ao[16], au[16];
#pragma unroll
    for (int m = 0; m < 16; ++m) { ai[m] = 0.f; ao[m] = 0.f; au[m] = 0.f; }

    for (int kc = 0; kc < H; kc += 8) {
        __syncthreads();
        for (int idx = tid; idx < 3 * H * 2; idx += 256) {
            int p   = idx / (H * 2);
            int rem = idx - p * (H * 2);
            int jj  = rem >> 1;
            int q   = rem & 1;
            ((float4*)w_s[p][jj])[q] =
                ((const float4*)(W_iou + (p * H + jj) * H + kc))[q];
        }
        __syncthreads();

        float w0[8], w1[8], w2[8];
#pragma unroll
        for (int q = 0; q < 2; ++q) {
            ((float4*)w0)[q] = ((float4*)w_s[0][j])[q];
            ((float4*)w1)[q] = ((float4*)w_s[1][j])[q];
            ((float4*)w2)[q] = ((float4*)w_s[2][j])[q];
        }
#pragma unroll
        for (int mi = 0; mi < 16; ++mi) {
            int m = mg * 16 + mi;
            float xc[8];
#pragma unroll
            for (int q = 0; q < 2; ++q) ((float4*)xc)[q] = ((float4*)&x_s[m][kc])[q];
#pragma unroll
            for (int q = 0; q < 8; ++q) {
                ai[mi] = fmaf(w0[q], xc[q], ai[mi]);
                ao[mi] = fmaf(w1[q], xc[q], ao[mi]);
                au[mi] = fmaf(w2[q], xc[q], au[mi]);
            }
        }
    }

    float bi = b_iou[j]         + b_Uiou[j];
    float bo = b_iou[H + j]     + b_Uiou[H + j];
    float bu = b_iou[2 * H + j] + b_Uiou[2 * H + j];
#pragma unroll
    for (int mi = 0; mi < 16; ++mi) {
        int m = mg * 16 + mi;
        int g = g0 + m;
        float iv = sig_(ai[mi] + bi);
        float ov = sig_(ao[mi] + bo);
        float uv = th_(au[mi] + bu);
        float cl = iv * uv;
        float hl = ov * th_(cl);
        h_cur[(size_t)g * H + j] = f2b(hl);
        c_cur[(size_t)g * H + j] = f2b(cl);
    }
}

// ---------------------------------------------------------------------------
// Internal-level kernel: 16 nodes/block, 256 threads.
// Children of level-local node g are rows 2g, 2g+1 of the previous level.
// ---------------------------------------------------------------------------
__global__ __launch_bounds__(256, 2) void internal_kernel(
    const int* __restrict__ wordid, const float* __restrict__ E,
    const float* __restrict__ W_iou, const float* __restrict__ b_iou,
    const float* __restrict__ U_iou, const float* __restrict__ b_Uiou,
    const float* __restrict__ W_f,  const float* __restrict__ b_Wf,
    const float* __restrict__ U_f,  const float* __restrict__ b_Uf,
    const bf16_t* __restrict__ h_prev, const bf16_t* __restrict__ c_prev,
    bf16_t* __restrict__ h_cur, bf16_t* __restrict__ c_cur,
    int level, int t0)
{
    __shared__ __align__(16) float x_s [16][H];
    __shared__ __align__(16) float h0_s[16][H];
    __shared__ __align__(16) float h1_s[16][H];
    __shared__ __align__(16) float w_s [8][H][8];   // 32 KB

    const int tid = threadIdx.x;
    const int g0  = blockIdx.x * 16;

    // stage x rows (fp32, float4)
    for (int idx = tid; idx < 16 * (H / 4); idx += 256) {
        int m = idx >> 5;
        int q = idx & 31;
        int g = g0 + m;
        int t = g >> level;
        int i = g - (t << level);
        int id = (t0 + t) * NPT + ((1 << level) - 1) + i;
        ((float4*)x_s[m])[q] = ((const float4*)(E + (long)wordid[id] * H))[q];
    }
    // stage children h rows (bf16 -> f32): 512 uint4 loads, 2 per thread
    // idx = m*32 + q*2 + c : node m, uint4-index q (16 per 128-elem row), child c
    for (int idx = tid; idx < 512; idx += 256) {
        int c = idx & 1;
        int q = (idx >> 1) & 15;
        int m = idx >> 5;
        int g = g0 + m;
        const bf16_t* src = h_prev + (size_t)(2 * g + c) * H + q * 8;
        uint4 raw = *(const uint4*)src;
        float* dst = (c ? h1_s[m] : h0_s[m]) + q * 8;
        dst[0] = b2f(raw.x & 0xffff); dst[1] = b2f(raw.x >> 16);
        dst[2] = b2f(raw.y & 0xffff); dst[3] = b2f(raw.y >> 16);
        dst[4] = b2f(raw.z & 0xffff); dst[5] = b2f(raw.z >> 16);
        dst[6] = b2f(raw.w & 0xffff); dst[7] = b2f(raw.w >> 16);
    }

    const int j  = tid & 127;
    const int mg = tid >> 7;
    float ai[8], ao[8], au[8], afx[8], af0[8], af1[8];
#pragma unroll
    for (int m = 0; m < 8; ++m) {
        ai[m] = 0.f; ao[m] = 0.f; au[m] = 0.f;
        afx[m] = 0.f; af0[m] = 0.f; af1[m] = 0.f;
    }

    for (int kc = 0; kc < H; kc += 8) {
        __syncthreads();
        // planes: 0..2 W_iou(i,o,u) | 3..5 U_iou(i,o,u) | 6 W_f | 7 U_f
        for (int idx = tid; idx < 8 * H * 2; idx += 256) {
            int p   = idx / (H * 2);
            int rem = idx - p * (H * 2);
            int jj  = rem >> 1;
            int q   = rem & 1;
            const float* src;
            if      (p < 3)  src = W_iou + (p * H + jj) * H;
            else if (p < 6)  src = U_iou + ((p - 3) * H + jj) * H;
            else if (p == 6) src = W_f + jj * H;
            else             src = U_f + jj * H;
            ((float4*)w_s[p][jj])[q] = ((const float4*)(src + kc))[q];
        }
        __syncthreads();

        float wv[8][8];
#pragma unroll
        for (int p = 0; p < 8; ++p)
#pragma unroll
            for (int q = 0; q < 2; ++q)
                ((float4*)wv[p])[q] = ((float4*)w_s[p][j])[q];

#pragma unroll
        for (int mi = 0; mi < 8; ++mi) {
            int m = mg * 8 + mi;
            float xc[8], h0c[8], h1c[8];
#pragma unroll
            for (int q = 0; q < 2; ++q) {
                ((float4*)xc)[q]  = ((float4*)&x_s [m][kc])[q];
                ((float4*)h0c)[q] = ((float4*)&h0_s[m][kc])[q];
                ((float4*)h1c)[q] = ((float4*)&h1_s[m][kc])[q];
            }
#pragma unroll
            for (int q = 0; q < 8; ++q) {
                float ht = h0c[q] + h1c[q];
                ai[mi]  = fmaf(wv[0][q], xc[q], fmaf(wv[3][q], ht, ai[mi]));
                ao[mi]  = fmaf(wv[1][q], xc[q], fmaf(wv[4][q], ht, ao[mi]));
                au[mi]  = fmaf(wv[2][q], xc[q], fmaf(wv[5][q], ht, au[mi]));
                afx[mi] = fmaf(wv[6][q], xc[q], afx[mi]);
                af0[mi] = fmaf(wv[7][q], h0c[q], af0[mi]);
                af1[mi] = fmaf(wv[7][q], h1c[q], af1[mi]);
            }
        }
    }

    float bi = b_iou[j]         + b_Uiou[j];
    float bo = b_iou[H + j]     + b_Uiou[H + j];
    float bu = b_iou[2 * H + j] + b_Uiou[2 * H + j];
    float bf = b_Wf[j] + b_Uf[j];
#pragma unroll
    for (int mi = 0; mi < 8; ++mi) {
        int m = mg * 8 + mi;
        int g = g0 + m;
        float iv = sig_(ai[mi] + bi);
        float ov = sig_(ao[mi] + bo);
        float uv = th_(au[mi] + bu);
        float f0 = sig_(afx[mi] + af0[mi] + bf);
        float f1 = sig_(afx[mi] + af1[mi] + bf);
        float cc0 = b2f(c_prev[(size_t)(2 * g)     * H + j]);
        float cc1 = b2f(c_prev[(size_t)(2 * g + 1) * H + j]);
        float cl = iv * uv + f0 * cc0 + f1 * cc1;
        float hl = ov * th_(cl);
        h_cur[(size_t)g * H + j] = f2b(hl);
        c_cur[(size_t)g * H + j] = f2b(cl);
    }
}

// ---------------------------------------------------------------------------
// Per-level logits: one wave per node
// ---------------------------------------------------------------------------
__global__ void logits_kernel(
    const bf16_t* __restrict__ h_cur, const float* __restrict__ W_out,
    const float* __restrict__ b_out, float* __restrict__ out,
    int level, int M, int t0)
{
    int wv     = (blockIdx.x * blockDim.x + threadIdx.x) >> 6;
    int lane   = threadIdx.x & 63;
    int nwaves = (gridDim.x * blockDim.x) >> 6;
    for (int g = wv; g < M; g += nwaves) {
        int t = g >> level;
        int i = g - (t << level);
        int id = (t0 + t) * NPT + ((1 << level) - 1) + i;
        float h0 = b2f(h_cur[(size_t)g * H + lane]);
        float h1 = b2f(h_cur[(size_t)g * H + 64 + lane]);
#pragma unroll
        for (int c = 0; c < 5; ++c) {
            float p = h0 * W_out[c * H + lane] + h1 * W_out[c * H + 64 + lane];
#pragma unroll
            for (int off = 32; off >= 1; off >>= 1) p += __shfl_xor(p, off, 64);
            if (lane == 0) out[(size_t)id * 5 + c] = p + b_out[c];
        }
    }
}

// ---------------------------------------------------------------------------
extern "C" void kernel_launch(void* const* d_in, const int* in_sizes, int n_in,
                              void* d_out, int out_size, void* d_ws, size_t ws_size,
                              hipStream_t stream)
{
    (void)in_sizes; (void)n_in; (void)out_size;
    const int*   wordid = (const int*)  d_in[0];
    const float* E      = (const float*)d_in[1];
    const float* W_iou  = (const float*)d_in[2];
    const float* b_iou  = (const float*)d_in[3];
    const float* U_iou  = (const float*)d_in[4];
    const float* b_Uiou = (const float*)d_in[5];
    const float* W_f    = (const float*)d_in[6];
    const float* b_Wf   = (const float*)d_in[7];
    const float* U_f    = (const float*)d_in[8];
    const float* b_Uf   = (const float*)d_in[9];
    const float* W_out  = (const float*)d_in[10];
    const float* b_out  = (const float*)d_in[11];
    float* out = (float*)d_out;

    // Adaptive tree-chunking so the bf16 h/c ping-pong buffers fit ws_size.
    // Per-chunk bytes = T * 393216 (T = trees per chunk).
    int C = 1;
    while (C < 32) {
        size_t need = (size_t)(NTREES / C) * 393216u;
        if (need <= ws_size) break;
        C <<= 1;
    }
    const int T = NTREES / C;

    const size_t rowsA = (size_t)T << 9;   // deepest odd level (l=9)
    const size_t rowsB = (size_t)T << 8;   // deepest even level (l=8)
    bf16_t* hA = (bf16_t*)d_ws;
    bf16_t* cA = hA + rowsA * H;
    bf16_t* hB = cA + rowsA * H;
    bf16_t* cB = hB + rowsB * H;

    for (int chunk = 0; chunk < C; ++chunk) {
        int t0 = chunk * T;
        for (int l = TDEPTH - 1; l >= 0; --l) {
            int M = T << l;
            bf16_t* h_cur  = (l & 1) ? hA : hB;
            bf16_t* c_cur  = (l & 1) ? cA : cB;
            bf16_t* h_prev = (l & 1) ? hB : hA;
            bf16_t* c_prev = (l & 1) ? cB : cA;

            if (l == TDEPTH - 1) {
                leaf_kernel<<<M / 32, 256, 0, stream>>>(
                    wordid, E, W_iou, b_iou, b_Uiou, h_cur, c_cur, t0);
            } else {
                internal_kernel<<<M / 16, 256, 0, stream>>>(
                    wordid, E, W_iou, b_iou, U_iou, b_Uiou,
                    W_f, b_Wf, U_f, b_Uf,
                    h_prev, c_prev, h_cur, c_cur, l, t0);
            }
            int blocks = (M / 4 < 4096) ? ((M + 3) / 4) : 4096;
            logits_kernel<<<blocks, 256, 0, stream>>>(h_cur, W_out, b_out, out, l, M, t0);
        }
    }
}

// Round 5
// 923.661 us; speedup vs baseline: 3.1276x; 3.1276x over previous
//
#include <hip/hip_runtime.h>

#define H 128
#define TDEPTH 10
#define NPT 1023      // nodes per tree
#define NTREES 512

typedef unsigned short bf16_t;
typedef __attribute__((ext_vector_type(8))) short bf16x8;   // 8 bf16 = 4 VGPR
typedef __attribute__((ext_vector_type(4))) float f32x4;

__device__ __forceinline__ float sig_(float x) { return 1.0f / (1.0f + __expf(-x)); }
__device__ __forceinline__ float th_(float x)  { return 1.0f - 2.0f / (__expf(2.0f * x) + 1.0f); }
__device__ __forceinline__ float b2f(bf16_t u) {
    union { float f; unsigned int u; } v; v.u = ((unsigned int)u) << 16; return v.f;
}
__device__ __forceinline__ bf16_t f2b(float f) {
    union { float f; unsigned int u; } v; v.f = f;
    return (bf16_t)((v.u + 0x7fffu + ((v.u >> 16) & 1u)) >> 16);   // RNE
}
__device__ __forceinline__ bf16x8 ldg8(const bf16_t* p) {
    return *reinterpret_cast<const bf16x8*>(p);
}
#define MFMA(a, b, c) __builtin_amdgcn_mfma_f32_16x16x32_bf16(a, b, c, 0, 0, 0)

// ---------------------------------------------------------------------------
// Pack weights to bf16: rows 0-383 W_iou | 384-767 U_iou | 768-895 W_f | 896-1023 U_f
// ---------------------------------------------------------------------------
__global__ void pack_weights(const float* __restrict__ W_iou, const float* __restrict__ U_iou,
                             const float* __restrict__ W_f,   const float* __restrict__ U_f,
                             bf16_t* __restrict__ Wb)
{
    int i = blockIdx.x * 256 + threadIdx.x;   // 0 .. 131071
    int row = i >> 7;
    float v;
    if      (row < 384) v = W_iou[i];
    else if (row < 768) v = U_iou[i - 384 * H];
    else if (row < 896) v = W_f  [i - 768 * H];
    else                v = U_f  [i - 896 * H];
    Wb[i] = f2b(v);
}

__global__ void pack_E(const float* __restrict__ E, bf16_t* __restrict__ Eb)
{
    int i = blockIdx.x * 256 + threadIdx.x;   // grid covers 32000*128 exactly
    Eb[i] = f2b(E[i]);
}

// ---------------------------------------------------------------------------
// Leaf level (l=9): iou = x @ W_iou^T; c = i*u; h = o*tanh(c); also hsum out.
// Block: 256 thr = 4 waves; 32 nodes/block; wave w = feature slice [32w,32w+32).
// ---------------------------------------------------------------------------
__global__ __launch_bounds__(256) void leaf_mfma(
    const int* __restrict__ wordid, const bf16_t* __restrict__ Eb,
    const bf16_t* __restrict__ Wb,
    const float* __restrict__ b_iou, const float* __restrict__ b_Uiou,
    bf16_t* __restrict__ h_cur, bf16_t* __restrict__ c_cur,
    bf16_t* __restrict__ hs_cur, int t0)
{
    const int level = TDEPTH - 1;
    const int tid  = threadIdx.x;
    const int lane = tid & 63;
    const int w    = tid >> 6;
    const int n0   = blockIdx.x * 32;
    const int l15  = lane & 15;
    const int kg   = lane >> 4;
    const int kbase = kg * 8;
    const int fr0  = w * 32 + l15;

    // word ids for the two node sub-tiles
    int nd0 = n0 + l15, nd1 = n0 + 16 + l15;
    int tA = nd0 >> level, iA = nd0 & ((1 << level) - 1);
    int tB = nd1 >> level, iB = nd1 & ((1 << level) - 1);
    int widA = wordid[(t0 + tA) * NPT + (1 << level) - 1 + iA];
    int widB = wordid[(t0 + tB) * NPT + (1 << level) - 1 + iB];

    f32x4 z = {0.f, 0.f, 0.f, 0.f};
    f32x4 acc_i[2][2] = {{z,z},{z,z}}, acc_o[2][2] = {{z,z},{z,z}}, acc_u[2][2] = {{z,z},{z,z}};

#pragma unroll
    for (int ks = 0; ks < 4; ++ks) {
        const int kc = ks * 32 + kbase;
        bf16x8 xa = ldg8(Eb + (size_t)widA * H + kc);
        bf16x8 xb = ldg8(Eb + (size_t)widB * H + kc);
#pragma unroll
        for (int nt = 0; nt < 2; ++nt) {
            const int fr = fr0 + nt * 16;
            bf16x8 Wi = ldg8(Wb + (size_t)(      fr) * H + kc);
            bf16x8 Wo = ldg8(Wb + (size_t)(128 + fr) * H + kc);
            bf16x8 Wu = ldg8(Wb + (size_t)(256 + fr) * H + kc);
            acc_i[nt][0] = MFMA(xa, Wi, acc_i[nt][0]);
            acc_i[nt][1] = MFMA(xb, Wi, acc_i[nt][1]);
            acc_o[nt][0] = MFMA(xa, Wo, acc_o[nt][0]);
            acc_o[nt][1] = MFMA(xb, Wo, acc_o[nt][1]);
            acc_u[nt][0] = MFMA(xa, Wu, acc_u[nt][0]);
            acc_u[nt][1] = MFMA(xb, Wu, acc_u[nt][1]);
        }
    }

#pragma unroll
    for (int nt = 0; nt < 2; ++nt) {
        const int feat = fr0 + nt * 16;
        float bi = b_iou[      feat] + b_Uiou[      feat];
        float bo = b_iou[128 + feat] + b_Uiou[128 + feat];
        float bu = b_iou[256 + feat] + b_Uiou[256 + feat];
#pragma unroll
        for (int mt = 0; mt < 2; ++mt) {
            float hpair = 0.f;
#pragma unroll
            for (int r = 0; r < 4; ++r) {
                int node = n0 + mt * 16 + kg * 4 + r;
                float iv = sig_(acc_i[nt][mt][r] + bi);
                float ov = sig_(acc_o[nt][mt][r] + bo);
                float uv = th_ (acc_u[nt][mt][r] + bu);
                float cl = iv * uv;
                float hl = ov * th_(cl);
                h_cur[(size_t)node * H + feat] = f2b(hl);
                c_cur[(size_t)node * H + feat] = f2b(cl);
                if (r & 1) hs_cur[(size_t)(node >> 1) * H + feat] = f2b(hpair + hl);
                else       hpair = hl;
            }
        }
    }
}

// ---------------------------------------------------------------------------
// Internal levels: full TreeLSTM cell via MFMA. 32 nodes/block, 4 waves.
// ---------------------------------------------------------------------------
__global__ __launch_bounds__(256) void internal_mfma(
    const int* __restrict__ wordid, const bf16_t* __restrict__ Eb,
    const bf16_t* __restrict__ Wb,
    const float* __restrict__ b_iou, const float* __restrict__ b_Uiou,
    const float* __restrict__ b_Wf,  const float* __restrict__ b_Uf,
    const bf16_t* __restrict__ h_prev, const bf16_t* __restrict__ c_prev,
    const bf16_t* __restrict__ hs_prev,
    bf16_t* __restrict__ h_cur, bf16_t* __restrict__ c_cur,
    bf16_t* __restrict__ hs_cur,
    int level, int t0, int write_hs)
{
    const int tid  = threadIdx.x;
    const int lane = tid & 63;
    const int w    = tid >> 6;
    const int n0   = blockIdx.x * 32;
    const int l15  = lane & 15;
    const int kg   = lane >> 4;
    const int kbase = kg * 8;
    const int fr0  = w * 32 + l15;

    int nd0 = n0 + l15, nd1 = n0 + 16 + l15;
    int tA = nd0 >> level, iA = nd0 & ((1 << level) - 1);
    int tB = nd1 >> level, iB = nd1 & ((1 << level) - 1);
    int widA = wordid[(t0 + tA) * NPT + (1 << level) - 1 + iA];
    int widB = wordid[(t0 + tB) * NPT + (1 << level) - 1 + iB];

    f32x4 z = {0.f, 0.f, 0.f, 0.f};
    f32x4 acc_i [2][2] = {{z,z},{z,z}}, acc_o [2][2] = {{z,z},{z,z}}, acc_u [2][2] = {{z,z},{z,z}};
    f32x4 acc_fx[2][2] = {{z,z},{z,z}}, acc_f0[2][2] = {{z,z},{z,z}}, acc_f1[2][2] = {{z,z},{z,z}};

#pragma unroll
    for (int ks = 0; ks < 4; ++ks) {
        const int kc = ks * 32 + kbase;
        bf16x8 xa  = ldg8(Eb + (size_t)widA * H + kc);
        bf16x8 xb  = ldg8(Eb + (size_t)widB * H + kc);
        bf16x8 hsa = ldg8(hs_prev + (size_t)nd0 * H + kc);
        bf16x8 hsb = ldg8(hs_prev + (size_t)nd1 * H + kc);
        bf16x8 h0a = ldg8(h_prev + ((size_t)(2 * nd0))     * H + kc);
        bf16x8 h0b = ldg8(h_prev + ((size_t)(2 * nd1))     * H + kc);
        bf16x8 h1a = ldg8(h_prev + ((size_t)(2 * nd0 + 1)) * H + kc);
        bf16x8 h1b = ldg8(h_prev + ((size_t)(2 * nd1 + 1)) * H + kc);
#pragma unroll
        for (int nt = 0; nt < 2; ++nt) {
            const int fr = fr0 + nt * 16;
            bf16x8 Wi = ldg8(Wb + (size_t)(      fr) * H + kc);
            bf16x8 Wo = ldg8(Wb + (size_t)(128 + fr) * H + kc);
            bf16x8 Wu = ldg8(Wb + (size_t)(256 + fr) * H + kc);
            bf16x8 Ui = ldg8(Wb + (size_t)(384 + fr) * H + kc);
            bf16x8 Uo = ldg8(Wb + (size_t)(512 + fr) * H + kc);
            bf16x8 Uu = ldg8(Wb + (size_t)(640 + fr) * H + kc);
            bf16x8 Wf = ldg8(Wb + (size_t)(768 + fr) * H + kc);
            bf16x8 Uf = ldg8(Wb + (size_t)(896 + fr) * H + kc);
            acc_i [nt][0] = MFMA(xa,  Wi, acc_i [nt][0]);
            acc_i [nt][1] = MFMA(xb,  Wi, acc_i [nt][1]);
            acc_i [nt][0] = MFMA(hsa, Ui, acc_i [nt][0]);
            acc_i [nt][1] = MFMA(hsb, Ui, acc_i [nt][1]);
            acc_o [nt][0] = MFMA(xa,  Wo, acc_o [nt][0]);
            acc_o [nt][1] = MFMA(xb,  Wo, acc_o [nt][1]);
            acc_o [nt][0] = MFMA(hsa, Uo, acc_o [nt][0]);
            acc_o [nt][1] = MFMA(hsb, Uo, acc_o [nt][1]);
            acc_u [nt][0] = MFMA(xa,  Wu, acc_u [nt][0]);
            acc_u [nt][1] = MFMA(xb,  Wu, acc_u [nt][1]);
            acc_u [nt][0] = MFMA(hsa, Uu, acc_u [nt][0]);
            acc_u [nt][1] = MFMA(hsb, Uu, acc_u [nt][1]);
            acc_fx[nt][0] = MFMA(xa,  Wf, acc_fx[nt][0]);
            acc_fx[nt][1] = MFMA(xb,  Wf, acc_fx[nt][1]);
            acc_f0[nt][0] = MFMA(h0a, Uf, acc_f0[nt][0]);
            acc_f0[nt][1] = MFMA(h0b, Uf, acc_f0[nt][1]);
            acc_f1[nt][0] = MFMA(h1a, Uf, acc_f1[nt][0]);
            acc_f1[nt][1] = MFMA(h1b, Uf, acc_f1[nt][1]);
        }
    }

#pragma unroll
    for (int nt = 0; nt < 2; ++nt) {
        const int feat = fr0 + nt * 16;
        float bi = b_iou[      feat] + b_Uiou[      feat];
        float bo = b_iou[128 + feat] + b_Uiou[128 + feat];
        float bu = b_iou[256 + feat] + b_Uiou[256 + feat];
        float bf = b_Wf[feat] + b_Uf[feat];
#pragma unroll
        for (int mt = 0; mt < 2; ++mt) {
            float hpair = 0.f;
#pragma unroll
            for (int r = 0; r < 4; ++r) {
                int node = n0 + mt * 16 + kg * 4 + r;
                float iv = sig_(acc_i[nt][mt][r] + bi);
                float ov = sig_(acc_o[nt][mt][r] + bo);
                float uv = th_ (acc_u[nt][mt][r] + bu);
                float fx = acc_fx[nt][mt][r];
                float f0 = sig_(fx + acc_f0[nt][mt][r] + bf);
                float f1 = sig_(fx + acc_f1[nt][mt][r] + bf);
                float c0 = b2f(c_prev[((size_t)(2 * node))     * H + feat]);
                float c1 = b2f(c_prev[((size_t)(2 * node + 1)) * H + feat]);
                float cl = iv * uv + f0 * c0 + f1 * c1;
                float hl = ov * th_(cl);
                h_cur[(size_t)node * H + feat] = f2b(hl);
                c_cur[(size_t)node * H + feat] = f2b(cl);
                if (r & 1) { if (write_hs) hs_cur[(size_t)(node >> 1) * H + feat] = f2b(hpair + hl); }
                else       hpair = hl;
            }
        }
    }
}

// ---------------------------------------------------------------------------
// Per-level logits: one wave per node
// ---------------------------------------------------------------------------
__global__ void logits_kernel(
    const bf16_t* __restrict__ h_cur, const float* __restrict__ W_out,
    const float* __restrict__ b_out, float* __restrict__ out,
    int level, int M, int t0)
{
    int wv     = (blockIdx.x * blockDim.x + threadIdx.x) >> 6;
    int lane   = threadIdx.x & 63;
    int nwaves = (gridDim.x * blockDim.x) >> 6;
    for (int g = wv; g < M; g += nwaves) {
        int t = g >> level;
        int i = g - (t << level);
        int id = (t0 + t) * NPT + ((1 << level) - 1) + i;
        float h0 = b2f(h_cur[(size_t)g * H + lane]);
        float h1 = b2f(h_cur[(size_t)g * H + 64 + lane]);
#pragma unroll
        for (int c = 0; c < 5; ++c) {
            float p = h0 * W_out[c * H + lane] + h1 * W_out[c * H + 64 + lane];
#pragma unroll
            for (int off = 32; off >= 1; off >>= 1) p += __shfl_xor(p, off, 64);
            if (lane == 0) out[(size_t)id * 5 + c] = p + b_out[c];
        }
    }
}

// ---------------------------------------------------------------------------
extern "C" void kernel_launch(void* const* d_in, const int* in_sizes, int n_in,
                              void* d_out, int out_size, void* d_ws, size_t ws_size,
                              hipStream_t stream)
{
    (void)in_sizes; (void)n_in; (void)out_size;
    const int*   wordid = (const int*)  d_in[0];
    const float* E      = (const float*)d_in[1];
    const float* W_iou  = (const float*)d_in[2];
    const float* b_iou  = (const float*)d_in[3];
    const float* U_iou  = (const float*)d_in[4];
    const float* b_Uiou = (const float*)d_in[5];
    const float* W_f    = (const float*)d_in[6];
    const float* b_Wf   = (const float*)d_in[7];
    const float* U_f    = (const float*)d_in[8];
    const float* b_Uf   = (const float*)d_in[9];
    const float* W_out  = (const float*)d_in[10];
    const float* b_out  = (const float*)d_in[11];
    float* out = (float*)d_out;

    // ws layout: Wb (256 KB) | Eb (8 MB) | per-chunk h/c/hsum ping-pong (bf16)
    bf16_t* Wb = (bf16_t*)d_ws;
    bf16_t* Eb = Wb + 1024 * H;
    bf16_t* dyn = Eb + (size_t)32000 * H;
    const size_t fixed_bytes = (1024 + 32000) * (size_t)H * 2;

    // per-tree dynamic bytes: hA(512)+cA(512)+hsA(256)+hB(256)+cB(256)+hsB(128)
    // = 1920 rows * 256 B = 491520
    int C = 1;
    while (C < 16 && fixed_bytes + (size_t)(NTREES / C) * 491520u > ws_size) C <<= 1;
    const int T = NTREES / C;

    bf16_t* hA  = dyn;
    bf16_t* cA  = hA  + (size_t)T * 512 * H;
    bf16_t* hsA = cA  + (size_t)T * 512 * H;
    bf16_t* hB  = hsA + (size_t)T * 256 * H;
    bf16_t* cB  = hB  + (size_t)T * 256 * H;
    bf16_t* hsB = cB  + (size_t)T * 256 * H;

    pack_weights<<<512, 256, 0, stream>>>(W_iou, U_iou, W_f, U_f, Wb);
    pack_E<<<16000, 256, 0, stream>>>(E, Eb);

    for (int chunk = 0; chunk < C; ++chunk) {
        int t0 = chunk * T;
        for (int l = TDEPTH - 1; l >= 0; --l) {
            int M = T << l;
            bf16_t* h_cur  = (l & 1) ? hA  : hB;
            bf16_t* c_cur  = (l & 1) ? cA  : cB;
            bf16_t* hs_cur = (l & 1) ? hsA : hsB;
            bf16_t* h_prev = (l & 1) ? hB  : hA;
            bf16_t* c_prev = (l & 1) ? cB  : cA;
            bf16_t* hs_prev= (l & 1) ? hsB : hsA;

            if (l == TDEPTH - 1) {
                leaf_mfma<<<M / 32, 256, 0, stream>>>(
                    wordid, Eb, Wb, b_iou, b_Uiou, h_cur, c_cur, hs_cur, t0);
            } else {
                internal_mfma<<<M / 32, 256, 0, stream>>>(
                    wordid, Eb, Wb, b_iou, b_Uiou, b_Wf, b_Uf,
                    h_prev, c_prev, hs_prev, h_cur, c_cur, hs_cur,
                    l, t0, l > 0 ? 1 : 0);
            }
            int blocks = (M / 4 < 4096) ? ((M + 3) / 4) : 4096;
            logits_kernel<<<blocks, 256, 0, stream>>>(h_cur, W_out, b_out, out, l, M, t0);
        }
    }
}

// Round 6
// 701.201 us; speedup vs baseline: 4.1199x; 1.3173x over previous
//
#include <hip/hip_runtime.h>

#define H 128
#define TDEPTH 10
#define NPT 1023      // nodes per tree
#define NTREES 512
#define PAD 136       // padded LDS row (bf16): 128 + 8 -> stride 272B, 2-way banks

typedef unsigned short bf16_t;
typedef __attribute__((ext_vector_type(8))) short bf16x8;   // 8 bf16 = 4 VGPR
typedef __attribute__((ext_vector_type(4))) float f32x4;

__device__ __forceinline__ float sig_(float x) { return 1.0f / (1.0f + __expf(-x)); }
__device__ __forceinline__ float th_(float x)  { return 1.0f - 2.0f / (__expf(2.0f * x) + 1.0f); }
__device__ __forceinline__ float b2f(bf16_t u) {
    union { float f; unsigned int u; } v; v.u = ((unsigned int)u) << 16; return v.f;
}
__device__ __forceinline__ bf16_t f2b(float f) {
    union { float f; unsigned int u; } v; v.f = f;
    return (bf16_t)((v.u + 0x7fffu + ((v.u >> 16) & 1u)) >> 16);   // RNE
}
__device__ __forceinline__ bf16x8 ldg8(const bf16_t* p) {
    return *reinterpret_cast<const bf16x8*>(p);
}
__device__ __forceinline__ bf16x8 lds8(const bf16_t* p) {
    return *reinterpret_cast<const bf16x8*>(p);
}
#define MFMA(a, b, c) __builtin_amdgcn_mfma_f32_16x16x32_bf16(a, b, c, 0, 0, 0)

// ---------------------------------------------------------------------------
// Weight pack, plane-interleaved: Wb[(feat*8 + p)*128 + k]
// p: 0 Wi | 1 Wo | 2 Wu | 3 Ui | 4 Uo | 5 Uu | 6 Wf | 7 Uf   (feat = row in [0,128))
// ---------------------------------------------------------------------------
__global__ void pack_weights(const float* __restrict__ W_iou, const float* __restrict__ U_iou,
                             const float* __restrict__ W_f,   const float* __restrict__ U_f,
                             bf16_t* __restrict__ Wb)
{
    int i = blockIdx.x * 256 + threadIdx.x;   // 0 .. 131071
    int k    = i & 127;
    int p    = (i >> 7) & 7;
    int feat = i >> 10;
    float v;
    switch (p) {
        case 0: v = W_iou[(      feat) * H + k]; break;
        case 1: v = W_iou[(128 + feat) * H + k]; break;
        case 2: v = W_iou[(256 + feat) * H + k]; break;
        case 3: v = U_iou[(      feat) * H + k]; break;
        case 4: v = U_iou[(128 + feat) * H + k]; break;
        case 5: v = U_iou[(256 + feat) * H + k]; break;
        case 6: v = W_f  [feat * H + k]; break;
        default: v = U_f [feat * H + k]; break;
    }
    Wb[i] = f2b(v);
}

__global__ void pack_E(const float* __restrict__ E, bf16_t* __restrict__ Eb)
{
    int i = blockIdx.x * 256 + threadIdx.x;
    Eb[i] = f2b(E[i]);
}

// ---------------------------------------------------------------------------
// Leaf (l=9): 64 nodes/block, 512 threads = 8 feat-waves (16 feats each).
// ---------------------------------------------------------------------------
__global__ __launch_bounds__(512, 4) void leaf_mfma(
    const int* __restrict__ wordid, const bf16_t* __restrict__ Eb,
    const bf16_t* __restrict__ Wb,
    const float* __restrict__ b_iou, const float* __restrict__ b_Uiou,
    bf16_t* __restrict__ h_cur, bf16_t* __restrict__ c_cur,
    bf16_t* __restrict__ hs_cur, int t0)
{
    const int level = TDEPTH - 1;
    __shared__ __align__(16) bf16_t x_s[64][PAD];

    const int tid = threadIdx.x;
    const int n0  = blockIdx.x * 64;

    for (int idx = tid; idx < 1024; idx += 512) {
        int q = idx & 15;
        int m = idx >> 4;
        int g = n0 + m;
        int t = g >> level, i = g & ((1 << level) - 1);
        int wid = wordid[(t0 + t) * NPT + (1 << level) - 1 + i];
        *(uint4*)&x_s[m][q * 8] = *(const uint4*)(Eb + (size_t)wid * H + q * 8);
    }
    __syncthreads();

    const int lane = tid & 63;
    const int w    = tid >> 6;
    const int l15  = lane & 15;
    const int kg   = lane >> 4;
    const int feat = w * 16 + l15;
    const bf16_t* wbase = Wb + (size_t)feat * 1024 + kg * 8;

    f32x4 z = {0.f, 0.f, 0.f, 0.f};
    f32x4 acc[3][4];
#pragma unroll
    for (int g = 0; g < 3; ++g)
#pragma unroll
        for (int m = 0; m < 4; ++m) acc[g][m] = z;

#pragma unroll
    for (int ks = 0; ks < 4; ++ks) {
        bf16x8 W0 = ldg8(wbase + ks * 32 + 0 * 128);
        bf16x8 W1 = ldg8(wbase + ks * 32 + 1 * 128);
        bf16x8 W2 = ldg8(wbase + ks * 32 + 2 * 128);
        const int kc = ks * 32 + kg * 8;
#pragma unroll
        for (int mt = 0; mt < 4; ++mt) {
            bf16x8 xa = lds8(&x_s[mt * 16 + l15][kc]);
            acc[0][mt] = MFMA(xa, W0, acc[0][mt]);
            acc[1][mt] = MFMA(xa, W1, acc[1][mt]);
            acc[2][mt] = MFMA(xa, W2, acc[2][mt]);
        }
    }

    float bi = b_iou[      feat] + b_Uiou[      feat];
    float bo = b_iou[128 + feat] + b_Uiou[128 + feat];
    float bu = b_iou[256 + feat] + b_Uiou[256 + feat];
#pragma unroll
    for (int mt = 0; mt < 4; ++mt) {
        float hpair = 0.f;
#pragma unroll
        for (int r = 0; r < 4; ++r) {
            int g = n0 + mt * 16 + kg * 4 + r;
            float iv = sig_(acc[0][mt][r] + bi);
            float ov = sig_(acc[1][mt][r] + bo);
            float uv = th_ (acc[2][mt][r] + bu);
            float cl = iv * uv;
            float hl = ov * th_(cl);
            h_cur[(size_t)g * H + feat] = f2b(hl);
            c_cur[(size_t)g * H + feat] = f2b(cl);
            if (r & 1) hs_cur[(size_t)(g >> 1) * H + feat] = f2b(hpair + hl);
            else       hpair = hl;
        }
    }
}

// ---------------------------------------------------------------------------
// Internal levels: 32 nodes/block, 512 threads = 8 feat-waves (16 feats each).
// All activations (x, hsum, h-children, c-children) staged in padded LDS.
// ---------------------------------------------------------------------------
__global__ __launch_bounds__(512, 4) void internal_mfma(
    const int* __restrict__ wordid, const bf16_t* __restrict__ Eb,
    const bf16_t* __restrict__ Wb,
    const float* __restrict__ b_iou, const float* __restrict__ b_Uiou,
    const float* __restrict__ b_Wf,  const float* __restrict__ b_Uf,
    const bf16_t* __restrict__ h_prev, const bf16_t* __restrict__ c_prev,
    const bf16_t* __restrict__ hs_prev,
    bf16_t* __restrict__ h_cur, bf16_t* __restrict__ c_cur,
    bf16_t* __restrict__ hs_cur,
    int level, int t0, int write_hs)
{
    __shared__ __align__(16) bf16_t x_s [32][PAD];
    __shared__ __align__(16) bf16_t hs_s[32][PAD];
    __shared__ __align__(16) bf16_t h0_s[32][PAD];
    __shared__ __align__(16) bf16_t h1_s[32][PAD];
    __shared__ __align__(16) bf16_t c0_s[32][PAD];
    __shared__ __align__(16) bf16_t c1_s[32][PAD];

    const int tid = threadIdx.x;
    const int n0  = blockIdx.x * 32;

    // stage 192 rows x 16 uint4 = 3072 uint4 (6 per thread), all coalesced
    for (int idx = tid; idx < 3072; idx += 512) {
        int q  = idx & 15;
        int rr = idx >> 4;          // 0..191
        uint4 v;
        bf16_t* dst;
        if (rr < 32) {
            int m = rr, g = n0 + m;
            int t = g >> level, i = g & ((1 << level) - 1);
            int wid = wordid[(t0 + t) * NPT + (1 << level) - 1 + i];
            v = *(const uint4*)(Eb + (size_t)wid * H + q * 8);
            dst = &x_s[m][0];
        } else if (rr < 64) {
            int m = rr - 32;
            v = *(const uint4*)(hs_prev + (size_t)(n0 + m) * H + q * 8);
            dst = &hs_s[m][0];
        } else if (rr < 128) {
            int l = rr - 64;
            v = *(const uint4*)(h_prev + (size_t)(2 * n0 + l) * H + q * 8);
            dst = (l & 1) ? &h1_s[l >> 1][0] : &h0_s[l >> 1][0];
        } else {
            int l = rr - 128;
            v = *(const uint4*)(c_prev + (size_t)(2 * n0 + l) * H + q * 8);
            dst = (l & 1) ? &c1_s[l >> 1][0] : &c0_s[l >> 1][0];
        }
        *(uint4*)(dst + q * 8) = v;
    }
    __syncthreads();

    const int lane = tid & 63;
    const int w    = tid >> 6;
    const int l15  = lane & 15;
    const int kg   = lane >> 4;
    const int feat = w * 16 + l15;
    const bf16_t* wbase = Wb + (size_t)feat * 1024 + kg * 8;

    f32x4 z = {0.f, 0.f, 0.f, 0.f};
    f32x4 acc[6][2];
#pragma unroll
    for (int g = 0; g < 6; ++g)
#pragma unroll
        for (int m = 0; m < 2; ++m) acc[g][m] = z;

#pragma unroll
    for (int ks = 0; ks < 4; ++ks) {
        bf16x8 W0 = ldg8(wbase + ks * 32 + 0 * 128);
        bf16x8 W1 = ldg8(wbase + ks * 32 + 1 * 128);
        bf16x8 W2 = ldg8(wbase + ks * 32 + 2 * 128);
        bf16x8 W3 = ldg8(wbase + ks * 32 + 3 * 128);
        bf16x8 W4 = ldg8(wbase + ks * 32 + 4 * 128);
        bf16x8 W5 = ldg8(wbase + ks * 32 + 5 * 128);
        bf16x8 W6 = ldg8(wbase + ks * 32 + 6 * 128);
        bf16x8 W7 = ldg8(wbase + ks * 32 + 7 * 128);
        const int kc = ks * 32 + kg * 8;
#pragma unroll
        for (int mt = 0; mt < 2; ++mt) {
            const int row = mt * 16 + l15;
            bf16x8 xa  = lds8(&x_s [row][kc]);
            bf16x8 hsa = lds8(&hs_s[row][kc]);
            bf16x8 h0a = lds8(&h0_s[row][kc]);
            bf16x8 h1a = lds8(&h1_s[row][kc]);
            acc[0][mt] = MFMA(hsa, W3, MFMA(xa, W0, acc[0][mt]));
            acc[1][mt] = MFMA(hsa, W4, MFMA(xa, W1, acc[1][mt]));
            acc[2][mt] = MFMA(hsa, W5, MFMA(xa, W2, acc[2][mt]));
            acc[3][mt] = MFMA(xa,  W6, acc[3][mt]);
            acc[4][mt] = MFMA(h0a, W7, acc[4][mt]);
            acc[5][mt] = MFMA(h1a, W7, acc[5][mt]);
        }
    }

    float bi = b_iou[      feat] + b_Uiou[      feat];
    float bo = b_iou[128 + feat] + b_Uiou[128 + feat];
    float bu = b_iou[256 + feat] + b_Uiou[256 + feat];
    float bf = b_Wf[feat] + b_Uf[feat];
#pragma unroll
    for (int mt = 0; mt < 2; ++mt) {
        float hpair = 0.f;
#pragma unroll
        for (int r = 0; r < 4; ++r) {
            int nb = mt * 16 + kg * 4 + r;
            int g  = n0 + nb;
            float iv = sig_(acc[0][mt][r] + bi);
            float ov = sig_(acc[1][mt][r] + bo);
            float uv = th_ (acc[2][mt][r] + bu);
            float fx = acc[3][mt][r];
            float f0 = sig_(fx + acc[4][mt][r] + bf);
            float f1 = sig_(fx + acc[5][mt][r] + bf);
            float c0 = b2f(c0_s[nb][feat]);
            float c1 = b2f(c1_s[nb][feat]);
            float cl = iv * uv + f0 * c0 + f1 * c1;
            float hl = ov * th_(cl);
            h_cur[(size_t)g * H + feat] = f2b(hl);
            c_cur[(size_t)g * H + feat] = f2b(cl);
            if (r & 1) { if (write_hs) hs_cur[(size_t)(g >> 1) * H + feat] = f2b(hpair + hl); }
            else       hpair = hl;
        }
    }
}

// ---------------------------------------------------------------------------
// Per-level logits: one wave per node
// ---------------------------------------------------------------------------
__global__ void logits_kernel(
    const bf16_t* __restrict__ h_cur, const float* __restrict__ W_out,
    const float* __restrict__ b_out, float* __restrict__ out,
    int level, int M, int t0)
{
    int wv     = (blockIdx.x * blockDim.x + threadIdx.x) >> 6;
    int lane   = threadIdx.x & 63;
    int nwaves = (gridDim.x * blockDim.x) >> 6;
    for (int g = wv; g < M; g += nwaves) {
        int t = g >> level;
        int i = g - (t << level);
        int id = (t0 + t) * NPT + ((1 << level) - 1) + i;
        float h0 = b2f(h_cur[(size_t)g * H + lane]);
        float h1 = b2f(h_cur[(size_t)g * H + 64 + lane]);
#pragma unroll
        for (int c = 0; c < 5; ++c) {
            float p = h0 * W_out[c * H + lane] + h1 * W_out[c * H + 64 + lane];
#pragma unroll
            for (int off = 32; off >= 1; off >>= 1) p += __shfl_xor(p, off, 64);
            if (lane == 0) out[(size_t)id * 5 + c] = p + b_out[c];
        }
    }
}

// ---------------------------------------------------------------------------
extern "C" void kernel_launch(void* const* d_in, const int* in_sizes, int n_in,
                              void* d_out, int out_size, void* d_ws, size_t ws_size,
                              hipStream_t stream)
{
    (void)in_sizes; (void)n_in; (void)out_size;
    const int*   wordid = (const int*)  d_in[0];
    const float* E      = (const float*)d_in[1];
    const float* W_iou  = (const float*)d_in[2];
    const float* b_iou  = (const float*)d_in[3];
    const float* U_iou  = (const float*)d_in[4];
    const float* b_Uiou = (const float*)d_in[5];
    const float* W_f    = (const float*)d_in[6];
    const float* b_Wf   = (const float*)d_in[7];
    const float* U_f    = (const float*)d_in[8];
    const float* b_Uf   = (const float*)d_in[9];
    const float* W_out  = (const float*)d_in[10];
    const float* b_out  = (const float*)d_in[11];
    float* out = (float*)d_out;

    // ws layout: Wb (256 KB) | Eb (8 MB) | per-chunk h/c/hsum ping-pong (bf16)
    bf16_t* Wb = (bf16_t*)d_ws;
    bf16_t* Eb = Wb + 1024 * H;
    bf16_t* dyn = Eb + (size_t)32000 * H;
    const size_t fixed_bytes = (1024 + 32000) * (size_t)H * 2;

    // per-tree dynamic bytes: hA(512)+cA(512)+hsA(256)+hB(256)+cB(256)+hsB(128)
    int C = 1;
    while (C < 16 && fixed_bytes + (size_t)(NTREES / C) * 491520u > ws_size) C <<= 1;
    const int T = NTREES / C;

    bf16_t* hA  = dyn;
    bf16_t* cA  = hA  + (size_t)T * 512 * H;
    bf16_t* hsA = cA  + (size_t)T * 512 * H;
    bf16_t* hB  = hsA + (size_t)T * 256 * H;
    bf16_t* cB  = hB  + (size_t)T * 256 * H;
    bf16_t* hsB = cB  + (size_t)T * 256 * H;

    pack_weights<<<512, 256, 0, stream>>>(W_iou, U_iou, W_f, U_f, Wb);
    pack_E<<<16000, 256, 0, stream>>>(E, Eb);

    for (int chunk = 0; chunk < C; ++chunk) {
        int t0 = chunk * T;
        for (int l = TDEPTH - 1; l >= 0; --l) {
            int M = T << l;
            bf16_t* h_cur  = (l & 1) ? hA  : hB;
            bf16_t* c_cur  = (l & 1) ? cA  : cB;
            bf16_t* hs_cur = (l & 1) ? hsA : hsB;
            bf16_t* h_prev = (l & 1) ? hB  : hA;
            bf16_t* c_prev = (l & 1) ? cB  : cA;
            bf16_t* hs_prev= (l & 1) ? hsB : hsA;

            if (l == TDEPTH - 1) {
                leaf_mfma<<<M / 64, 512, 0, stream>>>(
                    wordid, Eb, Wb, b_iou, b_Uiou, h_cur, c_cur, hs_cur, t0);
            } else {
                internal_mfma<<<M / 32, 512, 0, stream>>>(
                    wordid, Eb, Wb, b_iou, b_Uiou, b_Wf, b_Uf,
                    h_prev, c_prev, hs_prev, h_cur, c_cur, hs_cur,
                    l, t0, l > 0 ? 1 : 0);
            }
            int blocks = (M / 4 < 4096) ? ((M + 3) / 4) : 4096;
            logits_kernel<<<blocks, 256, 0, stream>>>(h_cur, W_out, b_out, out, l, M, t0);
        }
    }
}